// Round 6
// baseline (520.950 us; speedup 1.0000x reference)
//
#include <hip/hip_runtime.h>
#include <hip/hip_bf16.h>

#define N_NODES 100000
#define N_EDGES 1600000
#define OUTF 128
#define INF 256
#define SCAN_CHUNK 1024
#define SCAN_BLOCKS 98   // 98*1024 = 100352 >= 100000
#define M_TILES 6250     // 100000 / 16

#define CNT_BLOCKS 1563  // 1563*1024 >= 1.6M edges, 4 edges/thread
#define PROJ_BLOCKS 2500
#define SCAT_BLOCKS 1563

typedef _Float16 f16;
typedef _Float16 half8 __attribute__((ext_vector_type(8)));
typedef _Float16 half2v __attribute__((ext_vector_type(2)));
typedef float floatx4 __attribute__((ext_vector_type(4)));

// ---------------- convert W_mean|W_var into f16 Bt, wave-friendly layout ----------------
// Bt row ng = g*16 + i, g in [0,16): g = ch*8 + w*2 + cg; col = ch*64 + w*16 + i
// Separate (tiny) launch: must complete before count_proj reads Bt.
__global__ __launch_bounds__(256) void convert_B_kernel(const float* __restrict__ Wm,
                                                        const float* __restrict__ Wv,
                                                        f16* __restrict__ Bt) {
    int k = threadIdx.x;
    int ng = blockIdx.x;
    int g = ng >> 4, i = ng & 15;
    int ch = g >> 3, w = (g >> 1) & 3, cg = g & 1;
    int col = ch * 64 + w * 16 + i;
    const float* srcW = cg ? Wv : Wm;
    Bt[ng * 256 + k] = (f16)srcW[k * 128 + col];
}

// ---------------- fused: degree histogram + MFMA projection ----------------
// R6 restructure: proj no longer applies norm1/norm2 (deferred to agg), so it is
// INDEPENDENT of the count->scan chain. The 1.6M-atomic histogram (previously a
// serial ~100 us launch) now runs as role-split blocks UNDER proj's MFMA/LDS
// compute. Ids interleaved 8 proj : 5 count per 13.
// proj role: R3 structure (LDS dbuf staging via global_load_lds w=16, XOR swizzle,
// register-pinned B frags). msg[node] stores (m*att, v*att^2) pairs, f16.
// count role: pure histogram, 4 edges/thread, int4 dst loads (rank eliminated).
__global__ __launch_bounds__(256, 3) void count_proj_kernel(
        const float* __restrict__ feat, const f16* __restrict__ Bt,
        f16* __restrict__ msg,
        const int* __restrict__ dst, int E, int* __restrict__ deg) {
    __shared__ float As[2][16 * 256]; // 2 x 16 KB double buffer (proj role)

    int bid = blockIdx.x;
    int rr = bid % 13, q = bid / 13;
    int proj_id = -1, cnt_id = -1;
    if (rr < 8) {
        proj_id = q * 8 + rr;
        if (proj_id >= PROJ_BLOCKS) { cnt_id = 1560 + (proj_id - PROJ_BLOCKS); proj_id = -1; }
    } else {
        cnt_id = q * 5 + (rr - 8);
    }

    if (cnt_id >= 0) {
        // ---- histogram role ----
        int e0 = cnt_id * 1024 + threadIdx.x * 4;
        if (e0 + 3 < E) {
            int4 d4 = *(const int4*)(dst + e0);
            atomicAdd(&deg[d4.x], 1);
            atomicAdd(&deg[d4.y], 1);
            atomicAdd(&deg[d4.z], 1);
            atomicAdd(&deg[d4.w], 1);
        } else {
            for (int j = 0; j < 4; j++) {
                int e = e0 + j;
                if (e < E) atomicAdd(&deg[dst[e]], 1);
            }
        }
        return;
    }

    // ---- proj role ----
    int tid = threadIdx.x;
    int w = tid >> 6;
    int lane = tid & 63;
    int quad = lane >> 4;
    int l15 = lane & 15;
    int ch = proj_id & 1;
    int tbase = proj_id >> 1; // 0..1249

    // load B fragments once: 2 col-groups (mean/var, same 16 cols) x 8 k-frags
    half8 b[2][8];
#pragma unroll
    for (int cg = 0; cg < 2; cg++) {
        int g = ch * 8 + w * 2 + cg;
        const f16* bp = Bt + (size_t)(g * 16 + l15) * 256 + quad * 8;
#pragma unroll
        for (int kf = 0; kf < 8; kf++) {
            b[cg][kf] = *(const half8*)(bp + kf * 32);
        }
    }
    // pin: forces register residency across the loop (R2 evidence: VGPR=84 kept B)
#pragma unroll
    for (int cg = 0; cg < 2; cg++) {
#pragma unroll
        for (int kf = 0; kf < 8; kf++) {
            asm volatile("" : "+v"(b[cg][kf]));
        }
    }

    int col = ch * 64 + w * 16 + l15; // 0..127

    // swizzled ds_read byte addresses (row = l15): slot = X ^ ((row&7)<<4)
    int swz = (l15 & 7) << 4;
    int rb0 = l15 * 1024 + ((quad * 32) ^ swz);
    int rb1 = l15 * 1024 + ((quad * 32 + 16) ^ swz);
    int lsw = lane * 16;

    // wave w stages rows w*4 .. w*4+3 of each tile (1 KB per instruction)
    auto stage = [&](int buf, int t) {
        int m0 = t * 16;
#pragma unroll
        for (int j = 0; j < 4; j++) {
            int r = w * 4 + j;
            const char* gp = (const char*)(feat + (size_t)(m0 + r) * 256)
                             + (lsw ^ ((r & 7) << 4));
            char* lp = (char*)&As[buf][0] + r * 1024; // wave-uniform base
            __builtin_amdgcn_global_load_lds(
                (const __attribute__((address_space(1))) void*)gp,
                (__attribute__((address_space(3))) void*)lp, 16, 0, 0);
        }
    };

    stage(0, tbase);
    int cur = 0;

    for (int t = tbase; t < M_TILES; t += 1250) {
        __syncthreads(); // drains staging of buf[cur]

        int tn = t + 1250;
        if (tn < M_TILES) stage(cur ^ 1, tn); // in flight under this tile's compute

        const char* ab = (const char*)&As[cur][0];
        half8 a[8];
#pragma unroll
        for (int kf = 0; kf < 8; kf++) {
            floatx4 f0 = *(const floatx4*)(ab + rb0 + kf * 128);
            floatx4 f1 = *(const floatx4*)(ab + rb1 + kf * 128);
            half8 h;
            h[0] = (f16)f0.x; h[1] = (f16)f0.y; h[2] = (f16)f0.z; h[3] = (f16)f0.w;
            h[4] = (f16)f1.x; h[5] = (f16)f1.y; h[6] = (f16)f1.z; h[7] = (f16)f1.w;
            a[kf] = h;
        }

        floatx4 acc0 = (floatx4){0.f, 0.f, 0.f, 0.f};
        floatx4 acc1 = (floatx4){0.f, 0.f, 0.f, 0.f};
#pragma unroll
        for (int kf = 0; kf < 8; kf++) {
            acc0 = __builtin_amdgcn_mfma_f32_16x16x32_f16(a[kf], b[0][kf], acc0, 0, 0, 0);
            acc1 = __builtin_amdgcn_mfma_f32_16x16x32_f16(a[kf], b[1][kf], acc1, 0, 0, 0);
        }

        int m0 = t * 16;
        // epilogue: paired (m*att, v*att^2) 4 B stores — NO norm factors (deferred)
#pragma unroll
        for (int r = 0; r < 4; r++) {
            int node = m0 + quad * 4 + r;
            float m = fmaxf(acc0[r], 0.f);
            float v = fmaxf(acc1[r], 0.f);
            float att = __expf(-v); // GAMMA = 1
            half2v pr;
            pr[0] = (f16)(m * att);
            pr[1] = (f16)(v * att * att);
            *(half2v*)(msg + (size_t)node * 256 + col * 2) = pr;
        }
        cur ^= 1;
    }
}

// ---------------- scan step 1: per-chunk sums ----------------
__global__ __launch_bounds__(256) void scan_partial_kernel(const int* __restrict__ deg, int n,
                                                           int* __restrict__ partial) {
    __shared__ int red[256];
    int b = blockIdx.x, t = threadIdx.x;
    int base = b * SCAN_CHUNK;
    int s = 0;
    for (int i = t; i < SCAN_CHUNK; i += 256) {
        int idx = base + i;
        if (idx < n) s += deg[idx];
    }
    red[t] = s;
    __syncthreads();
    for (int off = 128; off > 0; off >>= 1) {
        if (t < off) red[t] += red[t + off];
        __syncthreads();
    }
    if (t == 0) partial[b] = red[0];
}

// ---------------- scan step 2: exclusive scan of partials (nb <= 128) ----------------
__global__ __launch_bounds__(128) void scan_top_kernel(int* __restrict__ partial, int nb,
                                                       int* __restrict__ row_start, int n) {
    __shared__ int sc[128];
    int t = threadIdx.x;
    int v = (t < nb) ? partial[t] : 0;
    sc[t] = v;
    __syncthreads();
    for (int off = 1; off < 128; off <<= 1) {
        int val = sc[t];
        int add = (t >= off) ? sc[t - off] : 0;
        __syncthreads();
        sc[t] = val + add;
        __syncthreads();
    }
    if (t < nb) partial[t] = sc[t] - v;   // exclusive
    if (t == 127) row_start[n] = sc[127]; // total edge count
}

// ---------------- scan step 3: per-chunk exclusive scan + norms + cursor init ------
__global__ __launch_bounds__(256) void scan_final_kernel(const int* __restrict__ deg, int n,
                                                         const int* __restrict__ partial,
                                                         int* __restrict__ row_start,
                                                         int* __restrict__ cursor,
                                                         float* __restrict__ norm1,
                                                         float* __restrict__ norm2) {
    __shared__ int sc[256];
    int b = blockIdx.x, t = threadIdx.x;
    int base = b * SCAN_CHUNK + t * 4;
    int v[4];
    int tsum = 0;
#pragma unroll
    for (int j = 0; j < 4; j++) {
        int idx = base + j;
        v[j] = (idx < n) ? deg[idx] : 0;
        tsum += v[j];
    }
    sc[t] = tsum;
    __syncthreads();
    for (int off = 1; off < 256; off <<= 1) {
        int val = sc[t];
        int add = (t >= off) ? sc[t - off] : 0;
        __syncthreads();
        sc[t] = val + add;
        __syncthreads();
    }
    int run = sc[t] - tsum + partial[b];
#pragma unroll
    for (int j = 0; j < 4; j++) {
        int idx = base + j;
        if (idx < n) {
            row_start[idx] = run;
            cursor[idx] = run;  // scatter's atomic cursor (rank array eliminated)
            float d = (float)(v[j] > 0 ? v[j] : 1); // clip(deg, 1)
            norm1[idx] = rsqrtf(d);
            norm2[idx] = 1.0f / d;
            run += v[j];
        }
    }
}

// ---------------- edge scatter into CSR slots (atomic cursor) ----------------
// pos = atomicAdd(cursor[dst]) merges rank generation into the scatter itself:
// -6.4 MB rank write + -6.4 MB rank read vs R5. Row-internal order becomes
// nondeterministic -- harmless, agg's fp32 row-sum is order-independent.
__global__ void scatter_kernel(const int* __restrict__ src, const int* __restrict__ dst,
                               int* __restrict__ cursor,
                               int E, int* __restrict__ srcs_sorted) {
    int e0 = blockIdx.x * 1024 + threadIdx.x * 4;
    if (e0 + 3 < E) {
        int4 s4 = *(const int4*)(src + e0);
        int4 d4 = *(const int4*)(dst + e0);
        srcs_sorted[atomicAdd(&cursor[d4.x], 1)] = s4.x;
        srcs_sorted[atomicAdd(&cursor[d4.y], 1)] = s4.y;
        srcs_sorted[atomicAdd(&cursor[d4.z], 1)] = s4.z;
        srcs_sorted[atomicAdd(&cursor[d4.w], 1)] = s4.w;
    } else {
        for (int j = 0; j < 4; j++) {
            int e = e0 + j;
            if (e < E) srcs_sorted[atomicAdd(&cursor[dst[e]], 1)] = src[e];
        }
    }
}

// ---------------- per-dst aggregation (wave per dst) + norms + final norm ----------
// msg rows now store (m*att, v*att^2) WITHOUT src-side norms; agg applies
// norm1[s]/norm2[s] per edge in fp32 (equal-or-better rounding than f16-pre-scale).
// 8-edge-deep gather: 128 B in flight per wave (2x R5) -- Little's-law lever for
// the latency component of the 4.1 TB/s plateau. Half-wave parity split as before.
__global__ __launch_bounds__(256) void agg_kernel(const int* __restrict__ row_start,
                                                  const int* __restrict__ srcs,
                                                  const f16* __restrict__ msg,
                                                  const float* __restrict__ norm1,
                                                  const float* __restrict__ norm2,
                                                  float* __restrict__ out_mean,
                                                  float* __restrict__ out_var) {
    int d = blockIdx.x * 4 + (threadIdx.x >> 6);
    int lane = threadIdx.x & 63;
    int half = lane >> 5;   // 0: even edges, 1: odd edges
    int jc = lane & 31;     // col group: cols 4jc..4jc+3

    int s0 = row_start[d];
    int s1 = row_start[d + 1];

    float am0 = 0.f, am1 = 0.f, am2 = 0.f, am3 = 0.f;
    float av0 = 0.f, av1 = 0.f, av2 = 0.f, av3 = 0.f;

    int i = s0 + half;
    // 8 edges per half-wave per iteration (16 total): 8 gathers + 16 scalar norm
    // loads in flight before any consume.
    for (; i + 14 < s1; i += 16) {
        int ss[8];
#pragma unroll
        for (int j = 0; j < 8; j++) ss[j] = srcs[i + 2 * j];
        half8 h[8];
        float n1v[8], n2v[8];
#pragma unroll
        for (int j = 0; j < 8; j++) {
            h[j] = *(const half8*)(msg + (size_t)ss[j] * 256 + jc * 8);
            n1v[j] = norm1[ss[j]];
            n2v[j] = norm2[ss[j]];
        }
#pragma unroll
        for (int j = 0; j < 8; j++) {
            am0 += (float)h[j][0] * n1v[j];
            av0 += (float)h[j][1] * n2v[j];
            am1 += (float)h[j][2] * n1v[j];
            av1 += (float)h[j][3] * n2v[j];
            am2 += (float)h[j][4] * n1v[j];
            av2 += (float)h[j][5] * n2v[j];
            am3 += (float)h[j][6] * n1v[j];
            av3 += (float)h[j][7] * n2v[j];
        }
    }
    for (; i < s1; i += 2) {
        int sa = srcs[i];
        half8 ha = *(const half8*)(msg + (size_t)sa * 256 + jc * 8);
        float n1 = norm1[sa], n2 = norm2[sa];
        am0 += (float)ha[0] * n1;
        av0 += (float)ha[1] * n2;
        am1 += (float)ha[2] * n1;
        av1 += (float)ha[3] * n2;
        am2 += (float)ha[4] * n1;
        av2 += (float)ha[5] * n2;
        am3 += (float)ha[6] * n1;
        av3 += (float)ha[7] * n2;
    }

    am0 += __shfl_xor(am0, 32, 64);
    am1 += __shfl_xor(am1, 32, 64);
    am2 += __shfl_xor(am2, 32, 64);
    am3 += __shfl_xor(am3, 32, 64);
    av0 += __shfl_xor(av0, 32, 64);
    av1 += __shfl_xor(av1, 32, 64);
    av2 += __shfl_xor(av2, 32, 64);
    av3 += __shfl_xor(av3, 32, 64);

    if (half == 0) {
        float k1 = norm1[d], k2 = norm2[d];
        floatx4 om = {am0 * k1, am1 * k1, am2 * k1, am3 * k1};
        floatx4 ov = {av0 * k2, av1 * k2, av2 * k2, av3 * k2};
        __builtin_nontemporal_store(om, (floatx4*)(out_mean + (size_t)d * 128 + jc * 4));
        __builtin_nontemporal_store(ov, (floatx4*)(out_var + (size_t)d * 128 + jc * 4));
    }
}

extern "C" void kernel_launch(void* const* d_in, const int* in_sizes, int n_in,
                              void* d_out, int out_size, void* d_ws, size_t ws_size,
                              hipStream_t stream) {
    const float* feat = (const float*)d_in[0];
    const float* Wm = (const float*)d_in[1];
    const float* Wv = (const float*)d_in[2];
    const int* src = (const int*)d_in[3];
    const int* dst = (const int*)d_in[4];
    float* out = (float*)d_out;

    const int N = N_NODES;
    const int E = N_EDGES;

    char* wsp = (char*)d_ws;
    auto carve = [&](size_t bytes) {
        char* p = wsp;
        wsp += (bytes + 255) & ~(size_t)255;
        return p;
    };
    f16* msg = (f16*)carve((size_t)N * 256 * sizeof(f16));   // (m,v) pairs, 51.2 MB
    f16* Bt = (f16*)carve((size_t)256 * 256 * sizeof(f16));  // 128 KB
    int* srcs_sorted = (int*)carve((size_t)E * 4);
    int* deg = (int*)carve((size_t)N * 4);
    int* row_start = (int*)carve((size_t)(N + 1) * 4);
    int* cursor = (int*)carve((size_t)N * 4);
    float* norm1 = (float*)carve((size_t)N * 4);
    float* norm2 = (float*)carve((size_t)N * 4);
    int* partial = (int*)carve(128 * 4);

    hipMemsetAsync(deg, 0, (size_t)N * 4, stream);

    convert_B_kernel<<<256, 256, 0, stream>>>(Wm, Wv, Bt);
    count_proj_kernel<<<PROJ_BLOCKS + CNT_BLOCKS, 256, 0, stream>>>(
        feat, Bt, msg, dst, E, deg);
    scan_partial_kernel<<<SCAN_BLOCKS, 256, 0, stream>>>(deg, N, partial);
    scan_top_kernel<<<1, 128, 0, stream>>>(partial, SCAN_BLOCKS, row_start, N);
    scan_final_kernel<<<SCAN_BLOCKS, 256, 0, stream>>>(deg, N, partial, row_start, cursor,
                                                       norm1, norm2);
    scatter_kernel<<<SCAT_BLOCKS, 256, 0, stream>>>(src, dst, cursor, E, srcs_sorted);
    agg_kernel<<<N / 4, 256, 0, stream>>>(row_start, srcs_sorted, msg, norm1, norm2,
                                          out, out + (size_t)N * OUTF);
}

// Round 7
// 416.877 us; speedup vs baseline: 1.2496x; 1.2496x over previous
//
#include <hip/hip_runtime.h>
#include <hip/hip_bf16.h>

#define N_NODES 100000
#define N_EDGES 1600000
#define OUTF 128
#define INF 256
#define SCAN_CHUNK 1024
#define SCAN_BLOCKS 98   // 98*1024 = 100352 >= 100000
#define M_TILES 6250     // 100000 / 16

#define CNT_BLOCKS 1563  // 1563*1024 >= 1.6M edges, 4 edges/thread @256thr
#define PROJ_UNITS 1250  // 1250 units x 5 tiles (512-thr blocks do both ch halves)
#define SCAT_UNITS 782   // 782*2048 >= 1.6M edges, 4 edges/thread @512thr
#define FUSE_GROUPS 157  // 157*8=1256>=1250 proj, 157*5=785>=782 scat

typedef _Float16 f16;
typedef _Float16 half8 __attribute__((ext_vector_type(8)));
typedef _Float16 half2v __attribute__((ext_vector_type(2)));
typedef float floatx4 __attribute__((ext_vector_type(4)));

// ---------------- fused degree count + edge rank + W->Bt convert (R5 form) --------
// blocks [0, CNT_BLOCKS): count role (4 edges/thread, int4). [CNT_BLOCKS, +256): convB.
// Bt row ng = g*16 + i, g in [0,16): g = ch*8 + wl*2 + cg; col = ch*64 + wl*16 + i
__global__ void count_convB_kernel(const int* __restrict__ dst, int E,
                                   int* __restrict__ deg, int* __restrict__ rank,
                                   const float* __restrict__ Wm,
                                   const float* __restrict__ Wv,
                                   f16* __restrict__ Bt) {
    int bid = blockIdx.x;
    if (bid >= CNT_BLOCKS) {
        int ng = bid - CNT_BLOCKS;
        int k = threadIdx.x;
        int g = ng >> 4, i = ng & 15;
        int ch = g >> 3, wl = (g >> 1) & 3, cg = g & 1;
        int col = ch * 64 + wl * 16 + i;
        const float* srcW = cg ? Wv : Wm;
        Bt[ng * 256 + k] = (f16)srcW[k * 128 + col];
        return;
    }
    int e0 = bid * 1024 + threadIdx.x * 4;
    if (e0 + 3 < E) {
        int4 d4 = *(const int4*)(dst + e0);
        int4 r4;
        r4.x = atomicAdd(&deg[d4.x], 1);
        r4.y = atomicAdd(&deg[d4.y], 1);
        r4.z = atomicAdd(&deg[d4.z], 1);
        r4.w = atomicAdd(&deg[d4.w], 1);
        *(int4*)(rank + e0) = r4;
    } else {
        for (int j = 0; j < 4; j++) {
            int e = e0 + j;
            if (e < E) rank[e] = atomicAdd(&deg[dst[e]], 1);
        }
    }
}

// ---------------- scan step 1: per-chunk sums ----------------
__global__ __launch_bounds__(256) void scan_partial_kernel(const int* __restrict__ deg, int n,
                                                           int* __restrict__ partial) {
    __shared__ int red[256];
    int b = blockIdx.x, t = threadIdx.x;
    int base = b * SCAN_CHUNK;
    int s = 0;
    for (int i = t; i < SCAN_CHUNK; i += 256) {
        int idx = base + i;
        if (idx < n) s += deg[idx];
    }
    red[t] = s;
    __syncthreads();
    for (int off = 128; off > 0; off >>= 1) {
        if (t < off) red[t] += red[t + off];
        __syncthreads();
    }
    if (t == 0) partial[b] = red[0];
}

// ---------------- scan step 2: exclusive scan of partials (nb <= 128) ----------------
__global__ __launch_bounds__(128) void scan_top_kernel(int* __restrict__ partial, int nb,
                                                       int* __restrict__ row_start, int n) {
    __shared__ int sc[128];
    int t = threadIdx.x;
    int v = (t < nb) ? partial[t] : 0;
    sc[t] = v;
    __syncthreads();
    for (int off = 1; off < 128; off <<= 1) {
        int val = sc[t];
        int add = (t >= off) ? sc[t - off] : 0;
        __syncthreads();
        sc[t] = val + add;
        __syncthreads();
    }
    if (t < nb) partial[t] = sc[t] - v;   // exclusive
    if (t == 127) row_start[n] = sc[127]; // total edge count
}

// ---------------- scan step 3: per-chunk exclusive scan + norms ----------------
__global__ __launch_bounds__(256) void scan_final_kernel(const int* __restrict__ deg, int n,
                                                         const int* __restrict__ partial,
                                                         int* __restrict__ row_start,
                                                         float* __restrict__ norm1,
                                                         float* __restrict__ norm2) {
    __shared__ int sc[256];
    int b = blockIdx.x, t = threadIdx.x;
    int base = b * SCAN_CHUNK + t * 4;
    int v[4];
    int tsum = 0;
#pragma unroll
    for (int j = 0; j < 4; j++) {
        int idx = base + j;
        v[j] = (idx < n) ? deg[idx] : 0;
        tsum += v[j];
    }
    sc[t] = tsum;
    __syncthreads();
    for (int off = 1; off < 256; off <<= 1) {
        int val = sc[t];
        int add = (t >= off) ? sc[t - off] : 0;
        __syncthreads();
        sc[t] = val + add;
        __syncthreads();
    }
    int run = sc[t] - tsum + partial[b];
#pragma unroll
    for (int j = 0; j < 4; j++) {
        int idx = base + j;
        if (idx < n) {
            row_start[idx] = run;
            float d = (float)(v[j] > 0 ? v[j] : 1); // clip(deg, 1)
            norm1[idx] = rsqrtf(d);
            norm2[idx] = 1.0f / d;
            run += v[j];
        }
    }
}

// ---------------- fused MFMA projection (512 thr, both ch halves) + CSR scatter -----
// R7: proj blocks are 512 threads (8 waves). Waves 0-3 compute cols 0-63 (ch=0),
// waves 4-7 cols 64-127 (ch=1), SHARING one staged A-tile: feat is staged ONCE per
// tile (R5 staged it twice, once per ch-half block). Same MFMA total, half the
// staging traffic and half the proj block count. LDS 32KB/block -> 2 blocks/CU.
// scatter role: R5's rank-based pure-store form (4 edges/thread, int4), interleaved
// 8 proj : 5 scatter per 13 ids so it hides under proj compute.
__global__ __launch_bounds__(512, 4) void proj_scatter_kernel(
        const float* __restrict__ feat, const f16* __restrict__ Bt,
        const float* __restrict__ norm1, const float* __restrict__ norm2,
        f16* __restrict__ msg,
        const int* __restrict__ src, const int* __restrict__ dst,
        const int* __restrict__ rank, const int* __restrict__ row_start,
        int E, int* __restrict__ srcs_sorted) {
    __shared__ float As[2][16 * 256]; // 2 x 16 KB double buffer (proj role)

    int bid = blockIdx.x;
    int rr = bid % 13, q = bid / 13;
    int proj_id = -1, scat_id = -1;
    if (rr < 8) {
        proj_id = q * 8 + rr;
        if (proj_id >= PROJ_UNITS) return; // 6 idle blocks
    } else {
        scat_id = q * 5 + (rr - 8);
        if (scat_id >= SCAT_UNITS) return; // 3 idle blocks
    }

    if (scat_id >= 0) {
        // ---- scatter role (512 thr x 4 edges) ----
        int e0 = scat_id * 2048 + threadIdx.x * 4;
        if (e0 + 3 < E) {
            int4 s4 = *(const int4*)(src + e0);
            int4 d4 = *(const int4*)(dst + e0);
            int4 r4 = *(const int4*)(rank + e0);
            srcs_sorted[row_start[d4.x] + r4.x] = s4.x;
            srcs_sorted[row_start[d4.y] + r4.y] = s4.y;
            srcs_sorted[row_start[d4.z] + r4.z] = s4.z;
            srcs_sorted[row_start[d4.w] + r4.w] = s4.w;
        } else {
            for (int j = 0; j < 4; j++) {
                int e = e0 + j;
                if (e < E) srcs_sorted[row_start[dst[e]] + rank[e]] = src[e];
            }
        }
        return;
    }

    // ---- proj role ----
    int tid = threadIdx.x;
    int w = tid >> 6;        // 0..7
    int ch = w >> 2;         // waves 0-3: ch0, waves 4-7: ch1
    int wl = w & 3;          // wave-local within ch group
    int lane = tid & 63;
    int quad = lane >> 4;
    int l15 = lane & 15;
    int tbase = proj_id;     // 0..1249

    // load B fragments once: 2 col-groups (mean/var, same 16 cols) x 8 k-frags
    half8 b[2][8];
#pragma unroll
    for (int cg = 0; cg < 2; cg++) {
        int g = ch * 8 + wl * 2 + cg;
        const f16* bp = Bt + (size_t)(g * 16 + l15) * 256 + quad * 8;
#pragma unroll
        for (int kf = 0; kf < 8; kf++) {
            b[cg][kf] = *(const half8*)(bp + kf * 32);
        }
    }
    // pin: forces register residency across the loop (R2 evidence: VGPR=84 kept B)
#pragma unroll
    for (int cg = 0; cg < 2; cg++) {
#pragma unroll
        for (int kf = 0; kf < 8; kf++) {
            asm volatile("" : "+v"(b[cg][kf]));
        }
    }

    int col = ch * 64 + wl * 16 + l15; // 0..127

    // swizzled ds_read byte addresses (row = l15): slot = X ^ ((row&7)<<4)
    int swz = (l15 & 7) << 4;
    int rb0 = l15 * 1024 + ((quad * 32) ^ swz);
    int rb1 = l15 * 1024 + ((quad * 32 + 16) ^ swz);
    int lsw = lane * 16;

    // 8 waves x 2 rows each stage the 16-row tile (1 KB per instruction)
    auto stage = [&](int buf, int t) {
        int m0 = t * 16;
#pragma unroll
        for (int j = 0; j < 2; j++) {
            int r = w * 2 + j;
            const char* gp = (const char*)(feat + (size_t)(m0 + r) * 256)
                             + (lsw ^ ((r & 7) << 4));
            char* lp = (char*)&As[buf][0] + r * 1024; // wave-uniform base
            __builtin_amdgcn_global_load_lds(
                (const __attribute__((address_space(1))) void*)gp,
                (__attribute__((address_space(3))) void*)lp, 16, 0, 0);
        }
    };

    stage(0, tbase);
    int cur = 0;

    for (int t = tbase; t < M_TILES; t += 1250) {
        __syncthreads(); // drains staging of buf[cur]

        int tn = t + 1250;
        if (tn < M_TILES) stage(cur ^ 1, tn); // in flight under this tile's compute

        const char* ab = (const char*)&As[cur][0];
        half8 a[8];
#pragma unroll
        for (int kf = 0; kf < 8; kf++) {
            floatx4 f0 = *(const floatx4*)(ab + rb0 + kf * 128);
            floatx4 f1 = *(const floatx4*)(ab + rb1 + kf * 128);
            half8 h;
            h[0] = (f16)f0.x; h[1] = (f16)f0.y; h[2] = (f16)f0.z; h[3] = (f16)f0.w;
            h[4] = (f16)f1.x; h[5] = (f16)f1.y; h[6] = (f16)f1.z; h[7] = (f16)f1.w;
            a[kf] = h;
        }

        int m0 = t * 16;
        float s1r[4], s2r[4];
#pragma unroll
        for (int r = 0; r < 4; r++) {
            int node = m0 + quad * 4 + r;
            s1r[r] = norm1[node];
            s2r[r] = norm2[node];
        }

        floatx4 acc0 = (floatx4){0.f, 0.f, 0.f, 0.f};
        floatx4 acc1 = (floatx4){0.f, 0.f, 0.f, 0.f};
#pragma unroll
        for (int kf = 0; kf < 8; kf++) {
            acc0 = __builtin_amdgcn_mfma_f32_16x16x32_f16(a[kf], b[0][kf], acc0, 0, 0, 0);
            acc1 = __builtin_amdgcn_mfma_f32_16x16x32_f16(a[kf], b[1][kf], acc1, 0, 0, 0);
        }

        // epilogue: paired (m,v) 4 B stores, norms applied here (R5 semantics)
#pragma unroll
        for (int r = 0; r < 4; r++) {
            int node = m0 + quad * 4 + r;
            float m = fmaxf(acc0[r], 0.f);
            float v = fmaxf(acc1[r], 0.f);
            float att = __expf(-v); // GAMMA = 1
            half2v pr;
            pr[0] = (f16)(m * att * s1r[r]);
            pr[1] = (f16)(v * att * att * s2r[r]);
            *(half2v*)(msg + (size_t)node * 256 + col * 2) = pr;
        }
        cur ^= 1;
    }
}

// ---------------- per-dst aggregation (wave per dst) + final norm ----------------
// R5 form (norms baked into msg): half-wave parity split, lane jc loads one half8
// (16 B = cols 4jc..4jc+3 as (m,v) pairs) per edge, 4 edges in flight.
// R7 delta: branch-free masked tail batch (<=3 edges/half predicated, clamped
// index + 0/1 weight) replaces the serial 2-at-a-time tail loop.
__global__ __launch_bounds__(256) void agg_kernel(const int* __restrict__ row_start,
                                                  const int* __restrict__ srcs,
                                                  const f16* __restrict__ msg,
                                                  const float* __restrict__ norm1,
                                                  const float* __restrict__ norm2,
                                                  float* __restrict__ out_mean,
                                                  float* __restrict__ out_var) {
    int d = blockIdx.x * 4 + (threadIdx.x >> 6);
    int lane = threadIdx.x & 63;
    int half = lane >> 5;   // 0: even edges, 1: odd edges
    int jc = lane & 31;     // col group: cols 4jc..4jc+3

    int s0 = row_start[d];
    int s1 = row_start[d + 1];

    float am0 = 0.f, am1 = 0.f, am2 = 0.f, am3 = 0.f;
    float av0 = 0.f, av1 = 0.f, av2 = 0.f, av3 = 0.f;

    int i = s0 + half;
    for (; i + 6 < s1; i += 8) {
        int sa = srcs[i], sb = srcs[i + 2], sc = srcs[i + 4], sd = srcs[i + 6];
        half8 ha = *(const half8*)(msg + (size_t)sa * 256 + jc * 8);
        half8 hb = *(const half8*)(msg + (size_t)sb * 256 + jc * 8);
        half8 hc = *(const half8*)(msg + (size_t)sc * 256 + jc * 8);
        half8 hd = *(const half8*)(msg + (size_t)sd * 256 + jc * 8);
        am0 += (float)ha[0] + (float)hb[0] + (float)hc[0] + (float)hd[0];
        av0 += (float)ha[1] + (float)hb[1] + (float)hc[1] + (float)hd[1];
        am1 += (float)ha[2] + (float)hb[2] + (float)hc[2] + (float)hd[2];
        av1 += (float)ha[3] + (float)hb[3] + (float)hc[3] + (float)hd[3];
        am2 += (float)ha[4] + (float)hb[4] + (float)hc[4] + (float)hd[4];
        av2 += (float)ha[5] + (float)hb[5] + (float)hc[5] + (float)hd[5];
        am3 += (float)ha[6] + (float)hb[6] + (float)hc[6] + (float)hd[6];
        av3 += (float)ha[7] + (float)hb[7] + (float)hc[7] + (float)hd[7];
    }
    if (i < s1) {
        // masked batch: up to 3 edges remain for this half
        int sa = srcs[i];
        int ib = i + 2, ic = i + 4;
        int sb = (ib < s1) ? srcs[ib] : sa;
        int sc = (ic < s1) ? srcs[ic] : sa;
        float wb = (ib < s1) ? 1.f : 0.f;
        float wc = (ic < s1) ? 1.f : 0.f;
        half8 ha = *(const half8*)(msg + (size_t)sa * 256 + jc * 8);
        half8 hb = *(const half8*)(msg + (size_t)sb * 256 + jc * 8);
        half8 hc = *(const half8*)(msg + (size_t)sc * 256 + jc * 8);
        am0 += (float)ha[0] + wb * (float)hb[0] + wc * (float)hc[0];
        av0 += (float)ha[1] + wb * (float)hb[1] + wc * (float)hc[1];
        am1 += (float)ha[2] + wb * (float)hb[2] + wc * (float)hc[2];
        av1 += (float)ha[3] + wb * (float)hb[3] + wc * (float)hc[3];
        am2 += (float)ha[4] + wb * (float)hb[4] + wc * (float)hc[4];
        av2 += (float)ha[5] + wb * (float)hb[5] + wc * (float)hc[5];
        am3 += (float)ha[6] + wb * (float)hb[6] + wc * (float)hc[6];
        av3 += (float)ha[7] + wb * (float)hb[7] + wc * (float)hc[7];
    }

    am0 += __shfl_xor(am0, 32, 64);
    am1 += __shfl_xor(am1, 32, 64);
    am2 += __shfl_xor(am2, 32, 64);
    am3 += __shfl_xor(am3, 32, 64);
    av0 += __shfl_xor(av0, 32, 64);
    av1 += __shfl_xor(av1, 32, 64);
    av2 += __shfl_xor(av2, 32, 64);
    av3 += __shfl_xor(av3, 32, 64);

    if (half == 0) {
        float k1 = norm1[d], k2 = norm2[d];
        floatx4 om = {am0 * k1, am1 * k1, am2 * k1, am3 * k1};
        floatx4 ov = {av0 * k2, av1 * k2, av2 * k2, av3 * k2};
        __builtin_nontemporal_store(om, (floatx4*)(out_mean + (size_t)d * 128 + jc * 4));
        __builtin_nontemporal_store(ov, (floatx4*)(out_var + (size_t)d * 128 + jc * 4));
    }
}

extern "C" void kernel_launch(void* const* d_in, const int* in_sizes, int n_in,
                              void* d_out, int out_size, void* d_ws, size_t ws_size,
                              hipStream_t stream) {
    const float* feat = (const float*)d_in[0];
    const float* Wm = (const float*)d_in[1];
    const float* Wv = (const float*)d_in[2];
    const int* src = (const int*)d_in[3];
    const int* dst = (const int*)d_in[4];
    float* out = (float*)d_out;

    const int N = N_NODES;
    const int E = N_EDGES;

    char* wsp = (char*)d_ws;
    auto carve = [&](size_t bytes) {
        char* p = wsp;
        wsp += (bytes + 255) & ~(size_t)255;
        return p;
    };
    f16* msg = (f16*)carve((size_t)N * 256 * sizeof(f16));   // (m,v) pairs, 51.2 MB
    f16* Bt = (f16*)carve((size_t)256 * 256 * sizeof(f16));  // 128 KB
    int* srcs_sorted = (int*)carve((size_t)E * 4);
    int* rank = (int*)carve((size_t)E * 4);
    int* deg = (int*)carve((size_t)N * 4);
    int* row_start = (int*)carve((size_t)(N + 1) * 4);
    float* norm1 = (float*)carve((size_t)N * 4);
    float* norm2 = (float*)carve((size_t)N * 4);
    int* partial = (int*)carve(128 * 4);

    hipMemsetAsync(deg, 0, (size_t)N * 4, stream);

    count_convB_kernel<<<CNT_BLOCKS + 256, 256, 0, stream>>>(dst, E, deg, rank, Wm, Wv, Bt);
    scan_partial_kernel<<<SCAN_BLOCKS, 256, 0, stream>>>(deg, N, partial);
    scan_top_kernel<<<1, 128, 0, stream>>>(partial, SCAN_BLOCKS, row_start, N);
    scan_final_kernel<<<SCAN_BLOCKS, 256, 0, stream>>>(deg, N, partial, row_start, norm1, norm2);
    proj_scatter_kernel<<<FUSE_GROUPS * 13, 512, 0, stream>>>(
        feat, Bt, norm1, norm2, msg, src, dst, rank, row_start, E, srcs_sorted);
    agg_kernel<<<N / 4, 256, 0, stream>>>(row_start, srcs_sorted, msg, norm1, norm2,
                                          out, out + (size_t)N * OUTF);
}